// Round 6
// baseline (87.607 us; speedup 1.0000x reference)
//
#include <hip/hip_runtime.h>

#define NQ 10

#if __has_builtin(__builtin_amdgcn_permlane16_swap)
#define HAVE_PLSWAP 1
#endif

// ---------- cross-lane helpers ----------
// lx<M>: value from lane^M.
//   1,2  : DPP quad_perm           (VALU)
//   8    : DPP row_ror:8           (VALU; (lane+-8)%16 == lane^8, self-inverse)
//   4,16 : ds_swizzle BitMode      (LDS pipe)
//   32   : __shfl_xor
template<int M>
__device__ __forceinline__ float lx(float v) {
    if constexpr (M == 1)
        return __int_as_float(__builtin_amdgcn_mov_dpp(__float_as_int(v), 0xB1, 0xF, 0xF, true));
    else if constexpr (M == 2)
        return __int_as_float(__builtin_amdgcn_mov_dpp(__float_as_int(v), 0x4E, 0xF, 0xF, true));
    else if constexpr (M == 8)
        return __int_as_float(__builtin_amdgcn_mov_dpp(__float_as_int(v), 0x128, 0xF, 0xF, true));
    else if constexpr (M == 4 || M == 16)
        return __int_as_float(__builtin_amdgcn_ds_swizzle(__float_as_int(v), (M << 10) | 0x1F));
    else
        return __shfl_xor(v, M, 64);
}

template<int M>
__device__ __forceinline__ float2 lx2(float2 v) {
    return make_float2(lx<M>(v.x), lx<M>(v.y));
}

// xch<M> (M=16,32): a <- value of a from lane^M, b <- value of b from lane^M,
// via DOUBLE permlane swap. Algebraically invariant to the HW swap direction:
// swap(A,B) then swap(B,A) yields (xor_M(A), xor_M(B)) under either
// "odd rows of dst <-> even rows of src" or the mirrored semantics.
// Builtin returns an ext_vector(2) of uint: [0]=new first operand, [1]=new second.
template<int M>
__device__ __forceinline__ void xch(float& a, float& b) {
#ifdef HAVE_PLSWAP
    if constexpr (M == 16) {
        auto r1 = __builtin_amdgcn_permlane16_swap(__float_as_uint(a), __float_as_uint(b), false, false);
        auto r2 = __builtin_amdgcn_permlane16_swap(r1[1], r1[0], false, false);
        a = __uint_as_float(r2[0]);
        b = __uint_as_float(r2[1]);
    } else {
        auto r1 = __builtin_amdgcn_permlane32_swap(__float_as_uint(a), __float_as_uint(b), false, false);
        auto r2 = __builtin_amdgcn_permlane32_swap(r1[1], r1[0], false, false);
        a = __uint_as_float(r2[0]);
        b = __uint_as_float(r2[1]);
    }
#else
    a = lx<M>(a);
    b = lx<M>(b);
#endif
}

__device__ __forceinline__ float2 cmul(float2 a, float2 b) {
    return make_float2(a.x * b.x - a.y * b.y, a.x * b.y + a.y * b.x);
}

__device__ __forceinline__ float2 bperm2(int addr, float2 v) {
    float2 r;
    r.x = __int_as_float(__builtin_amdgcn_ds_bpermute(addr, __float_as_int(v.x)));
    r.y = __int_as_float(__builtin_amdgcn_ds_bpermute(addr, __float_as_int(v.y)));
    return r;
}

// ---------- gates ----------
// Real RY on a LANE bit via generic exchange (masks 1,2,4,8), complex state.
template<int M>
__device__ __forceinline__ void ry_lane(float2 st[16], int lane, float c, float s) {
    const float cB = (lane & M) ? s : -s;
#pragma unroll
    for (int r = 0; r < 16; ++r) {
        float2 part = lx2<M>(st[r]);
        st[r].x = c * st[r].x + cB * part.x;
        st[r].y = c * st[r].y + cB * part.y;
    }
}

// Real RY on lane bit M (16 or 32) via paired permlane exchange, complex state.
template<int M>
__device__ __forceinline__ void ry_lane_x(float2 st[16], int lane, float c, float s) {
    const float cB = (lane & M) ? s : -s;
#pragma unroll
    for (int r = 0; r < 16; r += 2) {
        float pax = st[r].x, pay = st[r].y, pbx = st[r + 1].x, pby = st[r + 1].y;
        xch<M>(pax, pbx);
        xch<M>(pay, pby);
        st[r].x     = c * st[r].x     + cB * pax;
        st[r].y     = c * st[r].y     + cB * pay;
        st[r + 1].x = c * st[r + 1].x + cB * pbx;
        st[r + 1].y = c * st[r + 1].y + cB * pby;
    }
}

// Real-state variants.
template<int M>
__device__ __forceinline__ void ry_lane_r(float sr[16], int lane, float c, float s) {
    const float cB = (lane & M) ? s : -s;
#pragma unroll
    for (int r = 0; r < 16; ++r) {
        float part = lx<M>(sr[r]);
        sr[r] = c * sr[r] + cB * part;
    }
}

template<int M>
__device__ __forceinline__ void ry_lane_r_x(float sr[16], int lane, float c, float s) {
    const float cB = (lane & M) ? s : -s;
#pragma unroll
    for (int r = 0; r < 16; r += 2) {
        float pa = sr[r], pb = sr[r + 1];
        xch<M>(pa, pb);
        sr[r]     = c * sr[r]     + cB * pa;
        sr[r + 1] = c * sr[r + 1] + cB * pb;
    }
}

// Real RY on a REGISTER bit, real state.
template<int RB>
__device__ __forceinline__ void ry_reg_r(float sr[16], float c, float s) {
#pragma unroll
    for (int r = 0; r < 16; ++r) {
        if (r & RB) continue;
        float a0 = sr[r], a1 = sr[r | RB];
        sr[r]      = c * a0 - s * a1;
        sr[r | RB] = s * a0 + c * a1;
    }
}

// Real RY on a REGISTER bit, complex state.
template<int RB>
__device__ __forceinline__ void ry_reg(float2 st[16], float c, float s) {
#pragma unroll
    for (int r = 0; r < 16; ++r) {
        if (r & RB) continue;
        float2 a0 = st[r], a1 = st[r | RB];
        st[r].x = c * a0.x - s * a1.x;
        st[r].y = c * a0.y - s * a1.y;
        st[r | RB].x = s * a0.x + c * a1.x;
        st[r | RB].y = s * a0.y + c * a1.y;
    }
}

// CNOT: control lane bit MC, target register bit RB.
template<int MC, int RB>
__device__ __forceinline__ void cnot_lane_reg(float2 st[16], int lane) {
    const bool sel = (lane & MC) != 0;
#pragma unroll
    for (int r = 0; r < 16; ++r) {
        if (r & RB) continue;
        float2 lo = st[r], hi = st[r | RB];
        st[r]      = sel ? hi : lo;
        st[r | RB] = sel ? lo : hi;
    }
}

// CNOT: control register bit RC, target register bit RT — free permutation.
template<int RC, int RT>
__device__ __forceinline__ void cnot_reg_reg(float2 st[16]) {
#pragma unroll
    for (int r = 0; r < 16; ++r) {
        if ((r & RC) && !(r & RT)) {
            float2 t = st[r];
            st[r] = st[r | RT];
            st[r | RT] = t;
        }
    }
}

// CNOT(9,0): every ODD register gets xor-32; pair odd regs and use xch<32>.
__device__ __forceinline__ void cnot_q9_q0(float2 st[16]) {
#pragma unroll
    for (int i = 0; i < 4; ++i) {
        const int ra = 4 * i + 1, rb = 4 * i + 3;
        xch<32>(st[ra].x, st[rb].x);
        xch<32>(st[ra].y, st[rb].y);
    }
}

// 64-point Walsh-Hadamard across lanes.
__device__ __forceinline__ float wht64(float v, int lane) {
    float t;
    t = lx<1>(v);  v = (lane & 1)  ? (t - v) : (v + t);
    t = lx<2>(v);  v = (lane & 2)  ? (t - v) : (v + t);
    t = lx<4>(v);  v = (lane & 4)  ? (t - v) : (v + t);
    t = lx<8>(v);  v = (lane & 8)  ? (t - v) : (v + t);
    t = lx<16>(v); v = (lane & 16) ? (t - v) : (v + t);
    t = lx<32>(v); v = (lane & 32) ? (t - v) : (v + t);
    return v;
}

// ---------- main kernel: one wave per batch sample ----------
// State layout: s = lane*16 + r ; qubit q <-> state bit p = 9-q.
// Lane bits = state bits 9..4 (qubits 0..5), reg bits 3..0 (qubits 6..9).
__global__ __launch_bounds__(256)
void pqc_kernel(const float* __restrict__ x,
                const float* __restrict__ params,
                float* __restrict__ out, int B) {
    const int lane = threadIdx.x & 63;
    const int wave = threadIdx.x >> 6;
    const int b = blockIdx.x * 4 + wave;
    if (b >= B) return;

    // ---- encoding: |psi> = prod_q RY(x_q)|0> is a product state ----
    const float* xb = x + (long)b * NQ;
    float c0,s0,c1,s1,c2,s2,c3,s3,c4,s4,c5,s5,c6,s6,c7,s7,c8,s8,c9,s9;
    __sincosf(0.5f * xb[0], &s0, &c0);
    __sincosf(0.5f * xb[1], &s1, &c1);
    __sincosf(0.5f * xb[2], &s2, &c2);
    __sincosf(0.5f * xb[3], &s3, &c3);
    __sincosf(0.5f * xb[4], &s4, &c4);
    __sincosf(0.5f * xb[5], &s5, &c5);
    __sincosf(0.5f * xb[6], &s6, &c6);
    __sincosf(0.5f * xb[7], &s7, &c7);
    __sincosf(0.5f * xb[8], &s8, &c8);
    __sincosf(0.5f * xb[9], &s9, &c9);
    float laneprod = ((lane & 32) ? s0 : c0) * ((lane & 16) ? s1 : c1)
                   * ((lane & 8)  ? s2 : c2) * ((lane & 4)  ? s3 : c3)
                   * ((lane & 2)  ? s4 : c4) * ((lane & 1)  ? s5 : c5);
    float Ar[4] = { c6 * c7, c6 * s7, s6 * c7, s6 * s7 };
    float Br[4] = { c8 * c9, c8 * s9, s8 * c9, s8 * s9 };
    Ar[0] *= laneprod; Ar[1] *= laneprod; Ar[2] *= laneprod; Ar[3] *= laneprod;

    float sr[16];
#pragma unroll
    for (int r = 0; r < 16; ++r) sr[r] = Ar[r >> 2] * Br[r & 3];

    // ---- layer 0: RYs on a purely REAL state ----
    const float* p0 = params;
    float c, s;
    __sincosf(0.5f * p0[0], &s, &c); ry_lane_r_x<32>(sr, lane, c, s);
    __sincosf(0.5f * p0[1], &s, &c); ry_lane_r_x<16>(sr, lane, c, s);
    __sincosf(0.5f * p0[2], &s, &c); ry_lane_r<8>(sr, lane, c, s);
    __sincosf(0.5f * p0[3], &s, &c); ry_lane_r<4>(sr, lane, c, s);
    __sincosf(0.5f * p0[4], &s, &c); ry_lane_r<2>(sr, lane, c, s);
    __sincosf(0.5f * p0[5], &s, &c); ry_lane_r<1>(sr, lane, c, s);
    __sincosf(0.5f * p0[6], &s, &c); ry_reg_r<8>(sr, c, s);
    __sincosf(0.5f * p0[7], &s, &c); ry_reg_r<4>(sr, c, s);
    __sincosf(0.5f * p0[8], &s, &c); ry_reg_r<2>(sr, c, s);
    __sincosf(0.5f * p0[9], &s, &c); ry_reg_r<1>(sr, c, s);

    // ---- layer 0 fused Z-diagonal (real -> complex) ----
    float2 st[16];
    {
        float sz, cz;
        __sincosf(0.5f * p0[10], &sz, &cz);
        float2 PL = make_float2(cz, (lane & 32) ? sz : -sz);
        __sincosf(0.5f * p0[11], &sz, &cz);
        PL = cmul(PL, make_float2(cz, (lane & 16) ? sz : -sz));
        __sincosf(0.5f * p0[12], &sz, &cz);
        PL = cmul(PL, make_float2(cz, (lane & 8) ? sz : -sz));
        __sincosf(0.5f * p0[13], &sz, &cz);
        PL = cmul(PL, make_float2(cz, (lane & 4) ? sz : -sz));
        __sincosf(0.5f * p0[14], &sz, &cz);
        PL = cmul(PL, make_float2(cz, (lane & 2) ? sz : -sz));
        __sincosf(0.5f * p0[15], &sz, &cz);
        PL = cmul(PL, make_float2(cz, (lane & 1) ? sz : -sz));

        float z6s, z6c, z7s, z7c, z8s, z8c, z9s, z9c;
        __sincosf(0.5f * p0[16], &z6s, &z6c);
        __sincosf(0.5f * p0[17], &z7s, &z7c);
        __sincosf(0.5f * p0[18], &z8s, &z8c);
        __sincosf(0.5f * p0[19], &z9s, &z9c);
        float2 A[4], Bb[4];
        A[0] = cmul(make_float2(z6c, -z6s), make_float2(z7c, -z7s));
        A[1] = cmul(make_float2(z6c, -z6s), make_float2(z7c,  z7s));
        A[2] = cmul(make_float2(z6c,  z6s), make_float2(z7c, -z7s));
        A[3] = cmul(make_float2(z6c,  z6s), make_float2(z7c,  z7s));
        Bb[0] = cmul(make_float2(z8c, -z8s), make_float2(z9c, -z9s));
        Bb[1] = cmul(make_float2(z8c, -z8s), make_float2(z9c,  z9s));
        Bb[2] = cmul(make_float2(z8c,  z8s), make_float2(z9c, -z9s));
        Bb[3] = cmul(make_float2(z8c,  z8s), make_float2(z9c,  z9s));
        A[0] = cmul(A[0], PL); A[1] = cmul(A[1], PL);
        A[2] = cmul(A[2], PL); A[3] = cmul(A[3], PL);
#pragma unroll
        for (int r = 0; r < 16; ++r) {
            float2 t = make_float2(sr[r] * A[r >> 2].x, sr[r] * A[r >> 2].y);
            st[r] = cmul(t, Bb[r & 3]);
        }
    }

    // ---- layer 0 CNOT ring ----
    {
        const int addr = ((lane ^ (lane >> 1)) & 63) << 2;
#pragma unroll
        for (int r = 0; r < 16; ++r) st[r] = bperm2(addr, st[r]);
        cnot_lane_reg<1, 8>(st, lane);
        cnot_reg_reg<8, 4>(st);
        cnot_reg_reg<4, 2>(st);
        cnot_reg_reg<2, 1>(st);
        cnot_q9_q0(st);
    }

    // ---- layers 1..3 (complex). Last layer: diagonal+ring folded away. ----
#pragma unroll
    for (int l = 1; l < 4; ++l) {
        const float* pl = params + l * 2 * NQ;

        __sincosf(0.5f * pl[0], &s, &c); ry_lane_x<32>(st, lane, c, s);
        __sincosf(0.5f * pl[1], &s, &c); ry_lane_x<16>(st, lane, c, s);
        __sincosf(0.5f * pl[2], &s, &c); ry_lane<8>(st, lane, c, s);
        __sincosf(0.5f * pl[3], &s, &c); ry_lane<4>(st, lane, c, s);
        __sincosf(0.5f * pl[4], &s, &c); ry_lane<2>(st, lane, c, s);
        __sincosf(0.5f * pl[5], &s, &c); ry_lane<1>(st, lane, c, s);
        __sincosf(0.5f * pl[6], &s, &c); ry_reg<8>(st, c, s);
        __sincosf(0.5f * pl[7], &s, &c); ry_reg<4>(st, c, s);
        __sincosf(0.5f * pl[8], &s, &c); ry_reg<2>(st, c, s);
        __sincosf(0.5f * pl[9], &s, &c); ry_reg<1>(st, c, s);

        if (l < 3) {
            float sz, cz;
            __sincosf(0.5f * pl[10], &sz, &cz);
            float2 PL = make_float2(cz, (lane & 32) ? sz : -sz);
            __sincosf(0.5f * pl[11], &sz, &cz);
            PL = cmul(PL, make_float2(cz, (lane & 16) ? sz : -sz));
            __sincosf(0.5f * pl[12], &sz, &cz);
            PL = cmul(PL, make_float2(cz, (lane & 8) ? sz : -sz));
            __sincosf(0.5f * pl[13], &sz, &cz);
            PL = cmul(PL, make_float2(cz, (lane & 4) ? sz : -sz));
            __sincosf(0.5f * pl[14], &sz, &cz);
            PL = cmul(PL, make_float2(cz, (lane & 2) ? sz : -sz));
            __sincosf(0.5f * pl[15], &sz, &cz);
            PL = cmul(PL, make_float2(cz, (lane & 1) ? sz : -sz));

            float z6s, z6c, z7s, z7c, z8s, z8c, z9s, z9c;
            __sincosf(0.5f * pl[16], &z6s, &z6c);
            __sincosf(0.5f * pl[17], &z7s, &z7c);
            __sincosf(0.5f * pl[18], &z8s, &z8c);
            __sincosf(0.5f * pl[19], &z9s, &z9c);
            float2 A[4], Bb[4];
            A[0] = cmul(make_float2(z6c, -z6s), make_float2(z7c, -z7s));
            A[1] = cmul(make_float2(z6c, -z6s), make_float2(z7c,  z7s));
            A[2] = cmul(make_float2(z6c,  z6s), make_float2(z7c, -z7s));
            A[3] = cmul(make_float2(z6c,  z6s), make_float2(z7c,  z7s));
            Bb[0] = cmul(make_float2(z8c, -z8s), make_float2(z9c, -z9s));
            Bb[1] = cmul(make_float2(z8c, -z8s), make_float2(z9c,  z9s));
            Bb[2] = cmul(make_float2(z8c,  z8s), make_float2(z9c, -z9s));
            Bb[3] = cmul(make_float2(z8c,  z8s), make_float2(z9c,  z9s));
            A[0] = cmul(A[0], PL); A[1] = cmul(A[1], PL);
            A[2] = cmul(A[2], PL); A[3] = cmul(A[3], PL);
#pragma unroll
            for (int r = 0; r < 16; ++r)
                st[r] = cmul(cmul(st[r], A[r >> 2]), Bb[r & 3]);

            const int addr = ((lane ^ (lane >> 1)) & 63) << 2;
#pragma unroll
            for (int r = 0; r < 16; ++r) st[r] = bperm2(addr, st[r]);
            cnot_lane_reg<1, 8>(st, lane);
            cnot_reg_reg<8, 4>(st);
            cnot_reg_reg<4, 2>(st);
            cnot_reg_reg<2, 1>(st);
            cnot_q9_q0(st);
        }
    }

    // ---- readout (final ring folded into parity signs) ----
    float lane_sum = 0.f, A3 = 0.f, A32 = 0.f, A321 = 0.f, A3210 = 0.f;
#pragma unroll
    for (int r = 0; r < 16; ++r) {
        float p = st[r].x * st[r].x + st[r].y * st[r].y;
        const int p3 = (r >> 3) & 1;
        const int p32 = p3 ^ ((r >> 2) & 1);
        const int p321 = p32 ^ ((r >> 1) & 1);
        const int p3210 = p321 ^ (r & 1);
        lane_sum += p;
        A3    += p3    ? -p : p;
        A32   += p32   ? -p : p;
        A321  += p321  ? -p : p;
        A3210 += p3210 ? -p : p;
    }
    const float wLS   = wht64(lane_sum, lane);
    const float w3    = wht64(A3, lane);
    const float w32   = wht64(A32, lane);
    const float w321  = wht64(A321, lane);
    const float w3210 = wht64(A3210, lane);

    const long base = (long)b * NQ;
    if (lane == 31) out[base + 0] = w3210;
    if (lane == 48) out[base + 1] = wLS;
    if (lane == 56) out[base + 2] = wLS;
    if (lane == 60) out[base + 3] = wLS;
    if (lane == 62) out[base + 4] = wLS;
    if (lane == 63) {
        out[base + 5] = wLS;
        out[base + 6] = w3;
        out[base + 7] = w32;
        out[base + 8] = w321;
        out[base + 9] = w3210;
    }
}

extern "C" void kernel_launch(void* const* d_in, const int* in_sizes, int n_in,
                              void* d_out, int out_size, void* d_ws, size_t ws_size,
                              hipStream_t stream) {
    const float* x = (const float*)d_in[0];       // [B, 10]
    const float* params = (const float*)d_in[1];  // [4, 20]
    float* out = (float*)d_out;                   // [B, 10]
    const int B = in_sizes[0] / NQ;               // 4096
    const int grid = (B + 3) / 4;                 // 4 waves (samples) per block
    pqc_kernel<<<grid, 256, 0, stream>>>(x, params, out, B);
}

// Round 7
// 84.198 us; speedup vs baseline: 1.0405x; 1.0405x over previous
//
#include <hip/hip_runtime.h>

#define NQ 10

#if __has_builtin(__builtin_amdgcn_permlane16_swap)
#define HAVE_PLSWAP 1
#endif

// ---------- workspace layout (floats) ----------
// [0,80)      gate (cy,sy), index (l*10+q)*2
// [80,104)    Bb tables: (l*4+k)*2, l=0..2
// [112,1648)  Afold[l][lane][k] complex: offset 112 + (l*64+lane)*8 + k*2
// [2048, 2048+B*20)  enc (c,s) per sample/qubit
constexpr int GATE_OFF = 0;
constexpr int BB_OFF = 80;
constexpr int AFOLD_OFF = 112;
constexpr int ENC_OFF = 2048;

// ---------- cross-lane helpers ----------
// lx<M>: value from lane^M.
//   1,2 : DPP quad_perm         (VALU)
//   4   : DPP half_mirror(xor7) + quad_perm xor3   (2x VALU)
//   8   : DPP row_ror:8         (VALU)
//   16  : ds_swizzle            (readout only)
//   32  : __shfl_xor
template<int M>
__device__ __forceinline__ float lx(float v) {
    if constexpr (M == 1)
        return __int_as_float(__builtin_amdgcn_mov_dpp(__float_as_int(v), 0xB1, 0xF, 0xF, true));
    else if constexpr (M == 2)
        return __int_as_float(__builtin_amdgcn_mov_dpp(__float_as_int(v), 0x4E, 0xF, 0xF, true));
    else if constexpr (M == 4) {
        int t = __builtin_amdgcn_mov_dpp(__float_as_int(v), 0x141, 0xF, 0xF, true); // xor7
        return __int_as_float(__builtin_amdgcn_mov_dpp(t, 0x1B, 0xF, 0xF, true));   // xor3
    } else if constexpr (M == 8)
        return __int_as_float(__builtin_amdgcn_mov_dpp(__float_as_int(v), 0x128, 0xF, 0xF, true));
    else if constexpr (M == 16)
        return __int_as_float(__builtin_amdgcn_ds_swizzle(__float_as_int(v), (16 << 10) | 0x1F));
    else
        return __shfl_xor(v, M, 64);
}

template<int M>
__device__ __forceinline__ float2 lx2(float2 v) {
    return make_float2(lx<M>(v.x), lx<M>(v.y));
}

// xch<M> (M=16,32): both values fetched from lane^M via DOUBLE permlane swap
// (direction-invariant; verified R6).
template<int M>
__device__ __forceinline__ void xch(float& a, float& b) {
#ifdef HAVE_PLSWAP
    if constexpr (M == 16) {
        auto r1 = __builtin_amdgcn_permlane16_swap(__float_as_uint(a), __float_as_uint(b), false, false);
        auto r2 = __builtin_amdgcn_permlane16_swap(r1[1], r1[0], false, false);
        a = __uint_as_float(r2[0]);
        b = __uint_as_float(r2[1]);
    } else {
        auto r1 = __builtin_amdgcn_permlane32_swap(__float_as_uint(a), __float_as_uint(b), false, false);
        auto r2 = __builtin_amdgcn_permlane32_swap(r1[1], r1[0], false, false);
        a = __uint_as_float(r2[0]);
        b = __uint_as_float(r2[1]);
    }
#else
    a = lx<M>(a);
    b = lx<M>(b);
#endif
}

__device__ __forceinline__ float2 cmul(float2 a, float2 b) {
    return make_float2(a.x * b.x - a.y * b.y, a.x * b.y + a.y * b.x);
}

__device__ __forceinline__ float2 bperm2(int addr, float2 v) {
    float2 r;
    r.x = __int_as_float(__builtin_amdgcn_ds_bpermute(addr, __float_as_int(v.x)));
    r.y = __int_as_float(__builtin_amdgcn_ds_bpermute(addr, __float_as_int(v.y)));
    return r;
}

// ---------- gates ----------
template<int M>
__device__ __forceinline__ void ry_lane(float2 st[16], int lane, float c, float s) {
    const float cB = (lane & M) ? s : -s;
#pragma unroll
    for (int r = 0; r < 16; ++r) {
        float2 part = lx2<M>(st[r]);
        st[r].x = c * st[r].x + cB * part.x;
        st[r].y = c * st[r].y + cB * part.y;
    }
}

template<int M>
__device__ __forceinline__ void ry_lane_x(float2 st[16], int lane, float c, float s) {
    const float cB = (lane & M) ? s : -s;
#pragma unroll
    for (int r = 0; r < 16; r += 2) {
        float pax = st[r].x, pay = st[r].y, pbx = st[r + 1].x, pby = st[r + 1].y;
        xch<M>(pax, pbx);
        xch<M>(pay, pby);
        st[r].x     = c * st[r].x     + cB * pax;
        st[r].y     = c * st[r].y     + cB * pay;
        st[r + 1].x = c * st[r + 1].x + cB * pbx;
        st[r + 1].y = c * st[r + 1].y + cB * pby;
    }
}

template<int M>
__device__ __forceinline__ void ry_lane_r(float sr[16], int lane, float c, float s) {
    const float cB = (lane & M) ? s : -s;
#pragma unroll
    for (int r = 0; r < 16; ++r) {
        float part = lx<M>(sr[r]);
        sr[r] = c * sr[r] + cB * part;
    }
}

template<int M>
__device__ __forceinline__ void ry_lane_r_x(float sr[16], int lane, float c, float s) {
    const float cB = (lane & M) ? s : -s;
#pragma unroll
    for (int r = 0; r < 16; r += 2) {
        float pa = sr[r], pb = sr[r + 1];
        xch<M>(pa, pb);
        sr[r]     = c * sr[r]     + cB * pa;
        sr[r + 1] = c * sr[r + 1] + cB * pb;
    }
}

template<int RB>
__device__ __forceinline__ void ry_reg_r(float sr[16], float c, float s) {
#pragma unroll
    for (int r = 0; r < 16; ++r) {
        if (r & RB) continue;
        float a0 = sr[r], a1 = sr[r | RB];
        sr[r]      = c * a0 - s * a1;
        sr[r | RB] = s * a0 + c * a1;
    }
}

template<int RB>
__device__ __forceinline__ void ry_reg(float2 st[16], float c, float s) {
#pragma unroll
    for (int r = 0; r < 16; ++r) {
        if (r & RB) continue;
        float2 a0 = st[r], a1 = st[r | RB];
        st[r].x = c * a0.x - s * a1.x;
        st[r].y = c * a0.y - s * a1.y;
        st[r | RB].x = s * a0.x + c * a1.x;
        st[r | RB].y = s * a0.y + c * a1.y;
    }
}

template<int MC, int RB>
__device__ __forceinline__ void cnot_lane_reg(float2 st[16], int lane) {
    const bool sel = (lane & MC) != 0;
#pragma unroll
    for (int r = 0; r < 16; ++r) {
        if (r & RB) continue;
        float2 lo = st[r], hi = st[r | RB];
        st[r]      = sel ? hi : lo;
        st[r | RB] = sel ? lo : hi;
    }
}

template<int RC, int RT>
__device__ __forceinline__ void cnot_reg_reg(float2 st[16]) {
#pragma unroll
    for (int r = 0; r < 16; ++r) {
        if ((r & RC) && !(r & RT)) {
            float2 t = st[r];
            st[r] = st[r | RT];
            st[r | RT] = t;
        }
    }
}

__device__ __forceinline__ void cnot_q9_q0(float2 st[16]) {
#pragma unroll
    for (int i = 0; i < 4; ++i) {
        const int ra = 4 * i + 1, rb = 4 * i + 3;
        xch<32>(st[ra].x, st[rb].x);
        xch<32>(st[ra].y, st[rb].y);
    }
}

__device__ __forceinline__ float wht64(float v, int lane) {
    float t;
    t = lx<1>(v);  v = (lane & 1)  ? (t - v) : (v + t);
    t = lx<2>(v);  v = (lane & 2)  ? (t - v) : (v + t);
    t = lx<4>(v);  v = (lane & 4)  ? (t - v) : (v + t);
    t = lx<8>(v);  v = (lane & 8)  ? (t - v) : (v + t);
    t = lx<16>(v); v = (lane & 16) ? (t - v) : (v + t);
    t = lx<32>(v); v = (lane & 32) ? (t - v) : (v + t);
    return v;
}

// ---------- setup kernel: precompute batch-uniform tables + enc sincos ----------
__global__ __launch_bounds__(256)
void setup_kernel(const float* __restrict__ x, const float* __restrict__ params,
                  float* __restrict__ ws, int B) {
    const int t = threadIdx.x;
    const int g = blockIdx.x * 256 + t;
    if (g < B) {
        const float* xg = x + (long)g * NQ;
        float* e = ws + ENC_OFF + g * 2 * NQ;
#pragma unroll
        for (int q = 0; q < NQ; ++q) {
            float s, c;
            __sincosf(0.5f * xg[q], &s, &c);
            e[2 * q] = c;
            e[2 * q + 1] = s;
        }
    }
    if (blockIdx.x == 0) {
        if (t < 192) {
            // Afold[l][lane][k] = PL(l,lane) * A(l,k)
            const int l = t >> 6, lane = t & 63;
            const float* pl = params + l * 2 * NQ;
            float sz, cz;
            __sincosf(0.5f * pl[10], &sz, &cz);
            float2 PL = make_float2(cz, (lane & 32) ? sz : -sz);
            __sincosf(0.5f * pl[11], &sz, &cz);
            PL = cmul(PL, make_float2(cz, (lane & 16) ? sz : -sz));
            __sincosf(0.5f * pl[12], &sz, &cz);
            PL = cmul(PL, make_float2(cz, (lane & 8) ? sz : -sz));
            __sincosf(0.5f * pl[13], &sz, &cz);
            PL = cmul(PL, make_float2(cz, (lane & 4) ? sz : -sz));
            __sincosf(0.5f * pl[14], &sz, &cz);
            PL = cmul(PL, make_float2(cz, (lane & 2) ? sz : -sz));
            __sincosf(0.5f * pl[15], &sz, &cz);
            PL = cmul(PL, make_float2(cz, (lane & 1) ? sz : -sz));
            float s6, c6, s7, c7;
            __sincosf(0.5f * pl[16], &s6, &c6);
            __sincosf(0.5f * pl[17], &s7, &c7);
            float* dst = ws + AFOLD_OFF + (l * 64 + lane) * 8;
#pragma unroll
            for (int k = 0; k < 4; ++k) {
                float2 A = cmul(make_float2(c6, (k & 2) ? s6 : -s6),
                                make_float2(c7, (k & 1) ? s7 : -s7));
                A = cmul(A, PL);
                dst[2 * k] = A.x;
                dst[2 * k + 1] = A.y;
            }
        } else if (t < 232) {
            const int i = t - 192;  // l*10+q
            float s, c;
            __sincosf(0.5f * params[(i / 10) * 2 * NQ + (i % 10)], &s, &c);
            ws[GATE_OFF + i * 2] = c;
            ws[GATE_OFF + i * 2 + 1] = s;
        } else if (t < 244) {
            const int i = t - 232;  // l*4+k
            const int l = i >> 2, k = i & 3;
            const float* pl = params + l * 2 * NQ;
            float s8, c8, s9, c9;
            __sincosf(0.5f * pl[18], &s8, &c8);
            __sincosf(0.5f * pl[19], &s9, &c9);
            float2 v = cmul(make_float2(c8, (k & 2) ? s8 : -s8),
                            make_float2(c9, (k & 1) ? s9 : -s9));
            ws[BB_OFF + i * 2] = v.x;
            ws[BB_OFF + i * 2 + 1] = v.y;
        }
    }
}

// ---------- main kernel: one wave per batch sample ----------
// State layout: s = lane*16 + r ; qubit q <-> state bit p = 9-q.
template<bool WS>
__global__ __launch_bounds__(256)
void pqc_kernel(const float* __restrict__ x,
                const float* __restrict__ params,
                const float* __restrict__ ws,
                float* __restrict__ out, int B) {
    const int lane = threadIdx.x & 63;
    const int wave = threadIdx.x >> 6;
    const int b = blockIdx.x * 4 + wave;
    if (b >= B) return;

    // ---- encoding product state ----
    float c0,s0,c1,s1,c2,s2,c3,s3,c4,s4,c5,s5,c6,s6,c7,s7,c8,s8,c9,s9;
    if constexpr (WS) {
        const int sb = __builtin_amdgcn_readfirstlane(b);
        const float* e = ws + ENC_OFF + sb * 2 * NQ;
        c0 = e[0];  s0 = e[1];  c1 = e[2];  s1 = e[3];
        c2 = e[4];  s2 = e[5];  c3 = e[6];  s3 = e[7];
        c4 = e[8];  s4 = e[9];  c5 = e[10]; s5 = e[11];
        c6 = e[12]; s6 = e[13]; c7 = e[14]; s7 = e[15];
        c8 = e[16]; s8 = e[17]; c9 = e[18]; s9 = e[19];
    } else {
        const float* xb = x + (long)b * NQ;
        __sincosf(0.5f * xb[0], &s0, &c0);
        __sincosf(0.5f * xb[1], &s1, &c1);
        __sincosf(0.5f * xb[2], &s2, &c2);
        __sincosf(0.5f * xb[3], &s3, &c3);
        __sincosf(0.5f * xb[4], &s4, &c4);
        __sincosf(0.5f * xb[5], &s5, &c5);
        __sincosf(0.5f * xb[6], &s6, &c6);
        __sincosf(0.5f * xb[7], &s7, &c7);
        __sincosf(0.5f * xb[8], &s8, &c8);
        __sincosf(0.5f * xb[9], &s9, &c9);
    }
    float laneprod = ((lane & 32) ? s0 : c0) * ((lane & 16) ? s1 : c1)
                   * ((lane & 8)  ? s2 : c2) * ((lane & 4)  ? s3 : c3)
                   * ((lane & 2)  ? s4 : c4) * ((lane & 1)  ? s5 : c5);
    float Ar[4] = { c6 * c7, c6 * s7, s6 * c7, s6 * s7 };
    float Br[4] = { c8 * c9, c8 * s9, s8 * c9, s8 * s9 };
    Ar[0] *= laneprod; Ar[1] *= laneprod; Ar[2] *= laneprod; Ar[3] *= laneprod;

    float sr[16];
#pragma unroll
    for (int r = 0; r < 16; ++r) sr[r] = Ar[r >> 2] * Br[r & 3];

    // gate-angle accessor
    auto gate_cs = [&](int l, int q, float& c, float& s) {
        if constexpr (WS) {
            c = ws[GATE_OFF + (l * 10 + q) * 2];
            s = ws[GATE_OFF + (l * 10 + q) * 2 + 1];
        } else {
            __sincosf(0.5f * params[l * 2 * NQ + q], &s, &c);
        }
    };

    // diagonal tables accessor (A pre-folded with PL)
    float2 A[4], Bb[4];
    auto load_diag = [&](int l) {
        if constexpr (WS) {
            const float4* af = (const float4*)(ws + AFOLD_OFF) + (l * 64 + lane) * 2;
            float4 a01 = af[0], a23 = af[1];
            A[0] = make_float2(a01.x, a01.y);
            A[1] = make_float2(a01.z, a01.w);
            A[2] = make_float2(a23.x, a23.y);
            A[3] = make_float2(a23.z, a23.w);
            const float* bb = ws + BB_OFF + l * 8;
            Bb[0] = make_float2(bb[0], bb[1]);
            Bb[1] = make_float2(bb[2], bb[3]);
            Bb[2] = make_float2(bb[4], bb[5]);
            Bb[3] = make_float2(bb[6], bb[7]);
        } else {
            const float* pl = params + l * 2 * NQ;
            float sz, cz;
            __sincosf(0.5f * pl[10], &sz, &cz);
            float2 PL = make_float2(cz, (lane & 32) ? sz : -sz);
            __sincosf(0.5f * pl[11], &sz, &cz);
            PL = cmul(PL, make_float2(cz, (lane & 16) ? sz : -sz));
            __sincosf(0.5f * pl[12], &sz, &cz);
            PL = cmul(PL, make_float2(cz, (lane & 8) ? sz : -sz));
            __sincosf(0.5f * pl[13], &sz, &cz);
            PL = cmul(PL, make_float2(cz, (lane & 4) ? sz : -sz));
            __sincosf(0.5f * pl[14], &sz, &cz);
            PL = cmul(PL, make_float2(cz, (lane & 2) ? sz : -sz));
            __sincosf(0.5f * pl[15], &sz, &cz);
            PL = cmul(PL, make_float2(cz, (lane & 1) ? sz : -sz));
            float z6s, z6c, z7s, z7c, z8s, z8c, z9s, z9c;
            __sincosf(0.5f * pl[16], &z6s, &z6c);
            __sincosf(0.5f * pl[17], &z7s, &z7c);
            __sincosf(0.5f * pl[18], &z8s, &z8c);
            __sincosf(0.5f * pl[19], &z9s, &z9c);
#pragma unroll
            for (int k = 0; k < 4; ++k) {
                A[k] = cmul(cmul(make_float2(z6c, (k & 2) ? z6s : -z6s),
                                 make_float2(z7c, (k & 1) ? z7s : -z7s)), PL);
                Bb[k] = cmul(make_float2(z8c, (k & 2) ? z8s : -z8s),
                             make_float2(z9c, (k & 1) ? z9s : -z9s));
            }
        }
    };

    // ---- layer 0: RYs on a purely REAL state ----
    float c, s;
    gate_cs(0, 0, c, s); ry_lane_r_x<32>(sr, lane, c, s);
    gate_cs(0, 1, c, s); ry_lane_r_x<16>(sr, lane, c, s);
    gate_cs(0, 2, c, s); ry_lane_r<8>(sr, lane, c, s);
    gate_cs(0, 3, c, s); ry_lane_r<4>(sr, lane, c, s);
    gate_cs(0, 4, c, s); ry_lane_r<2>(sr, lane, c, s);
    gate_cs(0, 5, c, s); ry_lane_r<1>(sr, lane, c, s);
    gate_cs(0, 6, c, s); ry_reg_r<8>(sr, c, s);
    gate_cs(0, 7, c, s); ry_reg_r<4>(sr, c, s);
    gate_cs(0, 8, c, s); ry_reg_r<2>(sr, c, s);
    gate_cs(0, 9, c, s); ry_reg_r<1>(sr, c, s);

    // ---- layer 0 fused Z-diagonal (real -> complex) ----
    float2 st[16];
    load_diag(0);
#pragma unroll
    for (int r = 0; r < 16; ++r) {
        float2 t = make_float2(sr[r] * A[r >> 2].x, sr[r] * A[r >> 2].y);
        st[r] = cmul(t, Bb[r & 3]);
    }

    // ---- layer 0 CNOT ring ----
    {
        const int addr = ((lane ^ (lane >> 1)) & 63) << 2;
#pragma unroll
        for (int r = 0; r < 16; ++r) st[r] = bperm2(addr, st[r]);
        cnot_lane_reg<1, 8>(st, lane);
        cnot_reg_reg<8, 4>(st);
        cnot_reg_reg<4, 2>(st);
        cnot_reg_reg<2, 1>(st);
        cnot_q9_q0(st);
    }

    // ---- layers 1..3 (complex); last layer's diagonal+ring folded away ----
#pragma unroll
    for (int l = 1; l < 4; ++l) {
        gate_cs(l, 0, c, s); ry_lane_x<32>(st, lane, c, s);
        gate_cs(l, 1, c, s); ry_lane_x<16>(st, lane, c, s);
        gate_cs(l, 2, c, s); ry_lane<8>(st, lane, c, s);
        gate_cs(l, 3, c, s); ry_lane<4>(st, lane, c, s);
        gate_cs(l, 4, c, s); ry_lane<2>(st, lane, c, s);
        gate_cs(l, 5, c, s); ry_lane<1>(st, lane, c, s);
        gate_cs(l, 6, c, s); ry_reg<8>(st, c, s);
        gate_cs(l, 7, c, s); ry_reg<4>(st, c, s);
        gate_cs(l, 8, c, s); ry_reg<2>(st, c, s);
        gate_cs(l, 9, c, s); ry_reg<1>(st, c, s);

        if (l < 3) {
            load_diag(l);
#pragma unroll
            for (int r = 0; r < 16; ++r)
                st[r] = cmul(cmul(st[r], A[r >> 2]), Bb[r & 3]);

            const int addr = ((lane ^ (lane >> 1)) & 63) << 2;
#pragma unroll
            for (int r = 0; r < 16; ++r) st[r] = bperm2(addr, st[r]);
            cnot_lane_reg<1, 8>(st, lane);
            cnot_reg_reg<8, 4>(st);
            cnot_reg_reg<4, 2>(st);
            cnot_reg_reg<2, 1>(st);
            cnot_q9_q0(st);
        }
    }

    // ---- readout (final ring folded into parity signs) ----
    float lane_sum = 0.f, A3 = 0.f, A32 = 0.f, A321 = 0.f, A3210 = 0.f;
#pragma unroll
    for (int r = 0; r < 16; ++r) {
        float p = st[r].x * st[r].x + st[r].y * st[r].y;
        const int p3 = (r >> 3) & 1;
        const int p32 = p3 ^ ((r >> 2) & 1);
        const int p321 = p32 ^ ((r >> 1) & 1);
        const int p3210 = p321 ^ (r & 1);
        lane_sum += p;
        A3    += p3    ? -p : p;
        A32   += p32   ? -p : p;
        A321  += p321  ? -p : p;
        A3210 += p3210 ? -p : p;
    }
    const float wLS   = wht64(lane_sum, lane);
    const float w3    = wht64(A3, lane);
    const float w32   = wht64(A32, lane);
    const float w321  = wht64(A321, lane);
    const float w3210 = wht64(A3210, lane);

    const long base = (long)b * NQ;
    if (lane == 31) out[base + 0] = w3210;
    if (lane == 48) out[base + 1] = wLS;
    if (lane == 56) out[base + 2] = wLS;
    if (lane == 60) out[base + 3] = wLS;
    if (lane == 62) out[base + 4] = wLS;
    if (lane == 63) {
        out[base + 5] = wLS;
        out[base + 6] = w3;
        out[base + 7] = w32;
        out[base + 8] = w321;
        out[base + 9] = w3210;
    }
}

extern "C" void kernel_launch(void* const* d_in, const int* in_sizes, int n_in,
                              void* d_out, int out_size, void* d_ws, size_t ws_size,
                              hipStream_t stream) {
    const float* x = (const float*)d_in[0];       // [B, 10]
    const float* params = (const float*)d_in[1];  // [4, 20]
    float* out = (float*)d_out;                   // [B, 10]
    const int B = in_sizes[0] / NQ;               // 4096
    const int grid = (B + 3) / 4;                 // 4 waves (samples) per block

    const size_t needed = (size_t)(ENC_OFF + B * 2 * NQ) * sizeof(float);
    if (d_ws != nullptr && ws_size >= needed) {
        float* ws = (float*)d_ws;
        setup_kernel<<<(B + 255) / 256, 256, 0, stream>>>(x, params, ws, B);
        pqc_kernel<true><<<grid, 256, 0, stream>>>(x, params, ws, out, B);
    } else {
        pqc_kernel<false><<<grid, 256, 0, stream>>>(x, params, nullptr, out, B);
    }
}

// Round 8
// 82.807 us; speedup vs baseline: 1.0580x; 1.0168x over previous
//
#include <hip/hip_runtime.h>

#define NQ 10

#if __has_builtin(__builtin_amdgcn_permlane16_swap)
#define HAVE_PLSWAP 1
#endif

// ---------- cross-lane helpers ----------
// lx<M>: value from lane^M.
//   1,2 : DPP quad_perm                         (VALU)
//   4   : DPP half_mirror(xor7) + quad_perm xor3 (2x VALU)
//   8   : DPP row_ror:8                         (VALU)
//   16  : ds_swizzle (readout WHT only)
//   32  : __shfl_xor (readout WHT only)
template<int M>
__device__ __forceinline__ float lx(float v) {
    if constexpr (M == 1)
        return __int_as_float(__builtin_amdgcn_mov_dpp(__float_as_int(v), 0xB1, 0xF, 0xF, true));
    else if constexpr (M == 2)
        return __int_as_float(__builtin_amdgcn_mov_dpp(__float_as_int(v), 0x4E, 0xF, 0xF, true));
    else if constexpr (M == 4) {
        int t = __builtin_amdgcn_mov_dpp(__float_as_int(v), 0x141, 0xF, 0xF, true); // xor7
        return __int_as_float(__builtin_amdgcn_mov_dpp(t, 0x1B, 0xF, 0xF, true));   // xor3
    } else if constexpr (M == 8)
        return __int_as_float(__builtin_amdgcn_mov_dpp(__float_as_int(v), 0x128, 0xF, 0xF, true));
    else if constexpr (M == 16)
        return __int_as_float(__builtin_amdgcn_ds_swizzle(__float_as_int(v), (16 << 10) | 0x1F));
    else
        return __shfl_xor(v, M, 64);
}

template<int M>
__device__ __forceinline__ float2 lx2(float2 v) {
    return make_float2(lx<M>(v.x), lx<M>(v.y));
}

// xch<M> (M=16,32): both values fetched from lane^M via DOUBLE permlane swap
// (direction-invariant; verified R6).
template<int M>
__device__ __forceinline__ void xch(float& a, float& b) {
#ifdef HAVE_PLSWAP
    if constexpr (M == 16) {
        auto r1 = __builtin_amdgcn_permlane16_swap(__float_as_uint(a), __float_as_uint(b), false, false);
        auto r2 = __builtin_amdgcn_permlane16_swap(r1[1], r1[0], false, false);
        a = __uint_as_float(r2[0]);
        b = __uint_as_float(r2[1]);
    } else {
        auto r1 = __builtin_amdgcn_permlane32_swap(__float_as_uint(a), __float_as_uint(b), false, false);
        auto r2 = __builtin_amdgcn_permlane32_swap(r1[1], r1[0], false, false);
        a = __uint_as_float(r2[0]);
        b = __uint_as_float(r2[1]);
    }
#else
    a = lx<M>(a);
    b = lx<M>(b);
#endif
}

__device__ __forceinline__ float2 cmul(float2 a, float2 b) {
    return make_float2(a.x * b.x - a.y * b.y, a.x * b.y + a.y * b.x);
}

__device__ __forceinline__ float2 bperm2(int addr, float2 v) {
    float2 r;
    r.x = __int_as_float(__builtin_amdgcn_ds_bpermute(addr, __float_as_int(v.x)));
    r.y = __int_as_float(__builtin_amdgcn_ds_bpermute(addr, __float_as_int(v.y)));
    return r;
}

// ---------- gates ----------
template<int M>
__device__ __forceinline__ void ry_lane(float2 st[16], int lane, float c, float s) {
    const float cB = (lane & M) ? s : -s;
#pragma unroll
    for (int r = 0; r < 16; ++r) {
        float2 part = lx2<M>(st[r]);
        st[r].x = c * st[r].x + cB * part.x;
        st[r].y = c * st[r].y + cB * part.y;
    }
}

template<int M>
__device__ __forceinline__ void ry_lane_x(float2 st[16], int lane, float c, float s) {
    const float cB = (lane & M) ? s : -s;
#pragma unroll
    for (int r = 0; r < 16; r += 2) {
        float pax = st[r].x, pay = st[r].y, pbx = st[r + 1].x, pby = st[r + 1].y;
        xch<M>(pax, pbx);
        xch<M>(pay, pby);
        st[r].x     = c * st[r].x     + cB * pax;
        st[r].y     = c * st[r].y     + cB * pay;
        st[r + 1].x = c * st[r + 1].x + cB * pbx;
        st[r + 1].y = c * st[r + 1].y + cB * pby;
    }
}

template<int RB>
__device__ __forceinline__ void ry_reg(float2 st[16], float c, float s) {
#pragma unroll
    for (int r = 0; r < 16; ++r) {
        if (r & RB) continue;
        float2 a0 = st[r], a1 = st[r | RB];
        st[r].x = c * a0.x - s * a1.x;
        st[r].y = c * a0.y - s * a1.y;
        st[r | RB].x = s * a0.x + c * a1.x;
        st[r | RB].y = s * a0.y + c * a1.y;
    }
}

template<int MC, int RB>
__device__ __forceinline__ void cnot_lane_reg(float2 st[16], int lane) {
    const bool sel = (lane & MC) != 0;
#pragma unroll
    for (int r = 0; r < 16; ++r) {
        if (r & RB) continue;
        float2 lo = st[r], hi = st[r | RB];
        st[r]      = sel ? hi : lo;
        st[r | RB] = sel ? lo : hi;
    }
}

template<int RC, int RT>
__device__ __forceinline__ void cnot_reg_reg(float2 st[16]) {
#pragma unroll
    for (int r = 0; r < 16; ++r) {
        if ((r & RC) && !(r & RT)) {
            float2 t = st[r];
            st[r] = st[r | RT];
            st[r | RT] = t;
        }
    }
}

__device__ __forceinline__ void cnot_q9_q0(float2 st[16]) {
#pragma unroll
    for (int i = 0; i < 4; ++i) {
        const int ra = 4 * i + 1, rb = 4 * i + 3;
        xch<32>(st[ra].x, st[rb].x);
        xch<32>(st[ra].y, st[rb].y);
    }
}

__device__ __forceinline__ float wht64(float v, int lane) {
    float t;
    t = lx<1>(v);  v = (lane & 1)  ? (t - v) : (v + t);
    t = lx<2>(v);  v = (lane & 2)  ? (t - v) : (v + t);
    t = lx<4>(v);  v = (lane & 4)  ? (t - v) : (v + t);
    t = lx<8>(v);  v = (lane & 8)  ? (t - v) : (v + t);
    t = lx<16>(v); v = (lane & 16) ? (t - v) : (v + t);
    t = lx<32>(v); v = (lane & 32) ? (t - v) : (v + t);
    return v;
}

// ---------- main kernel: one wave per batch sample ----------
// State layout: s = lane*16 + r ; qubit q <-> state bit p = 9-q.
// Lane bits = state bits 9..4 (qubits 0..5), reg bits 3..0 (qubits 6..9).
__global__ __launch_bounds__(256)
void pqc_kernel(const float* __restrict__ x,
                const float* __restrict__ params,
                float* __restrict__ out, int B) {
    const int lane = threadIdx.x & 63;
    const int wave = threadIdx.x >> 6;
    const int b = blockIdx.x * 4 + wave;
    if (b >= B) return;

    // ---- encoding + ENTIRE layer 0 (RY+RZ) folded into a product state ----
    // RY(t)RY(x)|0> = RY(t+x)|0> = (cos h, sin h), h=(x+t)/2; then RZ phases:
    // u_q = (cos h * e^{-i hz}, sin h * e^{+i hz}).
    const float* xb = x + (long)b * NQ;
    const float* p0 = params;
    float a0,b0,a1,b1,a2,b2,a3,b3,a4,b4,a5,b5,a6,b6,a7,b7,a8,b8,a9,b9;
    float cz0,sz0,cz1,sz1,cz2,sz2,cz3,sz3,cz4,sz4,cz5,sz5,cz6,sz6,cz7,sz7,cz8,sz8,cz9,sz9;
    __sincosf(0.5f * (xb[0] + p0[0]), &b0, &a0);
    __sincosf(0.5f * (xb[1] + p0[1]), &b1, &a1);
    __sincosf(0.5f * (xb[2] + p0[2]), &b2, &a2);
    __sincosf(0.5f * (xb[3] + p0[3]), &b3, &a3);
    __sincosf(0.5f * (xb[4] + p0[4]), &b4, &a4);
    __sincosf(0.5f * (xb[5] + p0[5]), &b5, &a5);
    __sincosf(0.5f * (xb[6] + p0[6]), &b6, &a6);
    __sincosf(0.5f * (xb[7] + p0[7]), &b7, &a7);
    __sincosf(0.5f * (xb[8] + p0[8]), &b8, &a8);
    __sincosf(0.5f * (xb[9] + p0[9]), &b9, &a9);
    __sincosf(0.5f * p0[10], &sz0, &cz0);
    __sincosf(0.5f * p0[11], &sz1, &cz1);
    __sincosf(0.5f * p0[12], &sz2, &cz2);
    __sincosf(0.5f * p0[13], &sz3, &cz3);
    __sincosf(0.5f * p0[14], &sz4, &cz4);
    __sincosf(0.5f * p0[15], &sz5, &cz5);
    __sincosf(0.5f * p0[16], &sz6, &cz6);
    __sincosf(0.5f * p0[17], &sz7, &cz7);
    __sincosf(0.5f * p0[18], &sz8, &cz8);
    __sincosf(0.5f * p0[19], &sz9, &cz9);

    // lane factor: product over qubits 0..5 of u_q[lane bit]
    float R = ((lane & 32) ? b0 : a0) * ((lane & 16) ? b1 : a1)
            * ((lane & 8)  ? b2 : a2) * ((lane & 4)  ? b3 : a3)
            * ((lane & 2)  ? b4 : a4) * ((lane & 1)  ? b5 : a5);
    float2 P = make_float2(cz0, (lane & 32) ? sz0 : -sz0);
    P = cmul(P, make_float2(cz1, (lane & 16) ? sz1 : -sz1));
    P = cmul(P, make_float2(cz2, (lane & 8)  ? sz2 : -sz2));
    P = cmul(P, make_float2(cz3, (lane & 4)  ? sz3 : -sz3));
    P = cmul(P, make_float2(cz4, (lane & 2)  ? sz4 : -sz4));
    P = cmul(P, make_float2(cz5, (lane & 1)  ? sz5 : -sz5));
    float2 laneC = make_float2(R * P.x, R * P.y);

    // reg factors: qubits 6..9 (reg bits 8,4,2,1)
    float2 u6l = make_float2(a6 * cz6, -a6 * sz6), u6h = make_float2(b6 * cz6, b6 * sz6);
    float2 u7l = make_float2(a7 * cz7, -a7 * sz7), u7h = make_float2(b7 * cz7, b7 * sz7);
    float2 u8l = make_float2(a8 * cz8, -a8 * sz8), u8h = make_float2(b8 * cz8, b8 * sz8);
    float2 u9l = make_float2(a9 * cz9, -a9 * sz9), u9h = make_float2(b9 * cz9, b9 * sz9);
    float2 A2[4] = { cmul(u6l, u7l), cmul(u6l, u7h), cmul(u6h, u7l), cmul(u6h, u7h) };
    float2 B2[4] = { cmul(u8l, u9l), cmul(u8l, u9h), cmul(u8h, u9l), cmul(u8h, u9h) };
    float2 LA[4] = { cmul(laneC, A2[0]), cmul(laneC, A2[1]),
                     cmul(laneC, A2[2]), cmul(laneC, A2[3]) };

    float2 st[16];
#pragma unroll
    for (int r = 0; r < 16; ++r) st[r] = cmul(LA[r >> 2], B2[r & 3]);

    // ---- layer 0 CNOT ring ----
    {
        const int addr = ((lane ^ (lane >> 1)) & 63) << 2;
#pragma unroll
        for (int r = 0; r < 16; ++r) st[r] = bperm2(addr, st[r]);
        cnot_lane_reg<1, 8>(st, lane);
        cnot_reg_reg<8, 4>(st);
        cnot_reg_reg<4, 2>(st);
        cnot_reg_reg<2, 1>(st);
        cnot_q9_q0(st);
    }

    // ---- layers 1..3 (complex); last layer's diagonal+ring folded away ----
    float c, s;
#pragma unroll
    for (int l = 1; l < 4; ++l) {
        const float* pl = params + l * 2 * NQ;

        __sincosf(0.5f * pl[0], &s, &c); ry_lane_x<32>(st, lane, c, s);
        __sincosf(0.5f * pl[1], &s, &c); ry_lane_x<16>(st, lane, c, s);
        __sincosf(0.5f * pl[2], &s, &c); ry_lane<8>(st, lane, c, s);
        __sincosf(0.5f * pl[3], &s, &c); ry_lane<4>(st, lane, c, s);
        __sincosf(0.5f * pl[4], &s, &c); ry_lane<2>(st, lane, c, s);
        __sincosf(0.5f * pl[5], &s, &c); ry_lane<1>(st, lane, c, s);
        __sincosf(0.5f * pl[6], &s, &c); ry_reg<8>(st, c, s);
        __sincosf(0.5f * pl[7], &s, &c); ry_reg<4>(st, c, s);
        __sincosf(0.5f * pl[8], &s, &c); ry_reg<2>(st, c, s);
        __sincosf(0.5f * pl[9], &s, &c); ry_reg<1>(st, c, s);

        if (l < 3) {
            float sz, cz;
            __sincosf(0.5f * pl[10], &sz, &cz);
            float2 PL = make_float2(cz, (lane & 32) ? sz : -sz);
            __sincosf(0.5f * pl[11], &sz, &cz);
            PL = cmul(PL, make_float2(cz, (lane & 16) ? sz : -sz));
            __sincosf(0.5f * pl[12], &sz, &cz);
            PL = cmul(PL, make_float2(cz, (lane & 8) ? sz : -sz));
            __sincosf(0.5f * pl[13], &sz, &cz);
            PL = cmul(PL, make_float2(cz, (lane & 4) ? sz : -sz));
            __sincosf(0.5f * pl[14], &sz, &cz);
            PL = cmul(PL, make_float2(cz, (lane & 2) ? sz : -sz));
            __sincosf(0.5f * pl[15], &sz, &cz);
            PL = cmul(PL, make_float2(cz, (lane & 1) ? sz : -sz));

            float z6s, z6c, z7s, z7c, z8s, z8c, z9s, z9c;
            __sincosf(0.5f * pl[16], &z6s, &z6c);
            __sincosf(0.5f * pl[17], &z7s, &z7c);
            __sincosf(0.5f * pl[18], &z8s, &z8c);
            __sincosf(0.5f * pl[19], &z9s, &z9c);
            float2 A[4], Bb[4];
#pragma unroll
            for (int k = 0; k < 4; ++k) {
                A[k] = cmul(cmul(make_float2(z6c, (k & 2) ? z6s : -z6s),
                                 make_float2(z7c, (k & 1) ? z7s : -z7s)), PL);
                Bb[k] = cmul(make_float2(z8c, (k & 2) ? z8s : -z8s),
                             make_float2(z9c, (k & 1) ? z9s : -z9s));
            }
#pragma unroll
            for (int r = 0; r < 16; ++r)
                st[r] = cmul(cmul(st[r], A[r >> 2]), Bb[r & 3]);

            const int addr = ((lane ^ (lane >> 1)) & 63) << 2;
#pragma unroll
            for (int r = 0; r < 16; ++r) st[r] = bperm2(addr, st[r]);
            cnot_lane_reg<1, 8>(st, lane);
            cnot_reg_reg<8, 4>(st);
            cnot_reg_reg<4, 2>(st);
            cnot_reg_reg<2, 1>(st);
            cnot_q9_q0(st);
        }
    }

    // ---- readout (final ring folded into parity signs) ----
    float lane_sum = 0.f, A3 = 0.f, A32 = 0.f, A321 = 0.f, A3210 = 0.f;
#pragma unroll
    for (int r = 0; r < 16; ++r) {
        float p = st[r].x * st[r].x + st[r].y * st[r].y;
        const int p3 = (r >> 3) & 1;
        const int p32 = p3 ^ ((r >> 2) & 1);
        const int p321 = p32 ^ ((r >> 1) & 1);
        const int p3210 = p321 ^ (r & 1);
        lane_sum += p;
        A3    += p3    ? -p : p;
        A32   += p32   ? -p : p;
        A321  += p321  ? -p : p;
        A3210 += p3210 ? -p : p;
    }
    const float wLS   = wht64(lane_sum, lane);
    const float w3    = wht64(A3, lane);
    const float w32   = wht64(A32, lane);
    const float w321  = wht64(A321, lane);
    const float w3210 = wht64(A3210, lane);

    const long base = (long)b * NQ;
    if (lane == 31) out[base + 0] = w3210;
    if (lane == 48) out[base + 1] = wLS;
    if (lane == 56) out[base + 2] = wLS;
    if (lane == 60) out[base + 3] = wLS;
    if (lane == 62) out[base + 4] = wLS;
    if (lane == 63) {
        out[base + 5] = wLS;
        out[base + 6] = w3;
        out[base + 7] = w32;
        out[base + 8] = w321;
        out[base + 9] = w3210;
    }
}

extern "C" void kernel_launch(void* const* d_in, const int* in_sizes, int n_in,
                              void* d_out, int out_size, void* d_ws, size_t ws_size,
                              hipStream_t stream) {
    const float* x = (const float*)d_in[0];       // [B, 10]
    const float* params = (const float*)d_in[1];  // [4, 20]
    float* out = (float*)d_out;                   // [B, 10]
    const int B = in_sizes[0] / NQ;               // 4096
    const int grid = (B + 3) / 4;                 // 4 waves (samples) per block
    pqc_kernel<<<grid, 256, 0, stream>>>(x, params, out, B);
}